// Round 8
// baseline (194.763 us; speedup 1.0000x reference)
//
#include <hip/hip_runtime.h>

// Problem constants (match reference)
#define LSEQ 2048   // sequence length
#define NS   1022   // number of distances s = 2..1023
#define NF   5110   // NS * 5 output features
#define NB   8      // batch
#define IT   64     // i-positions per block
#define GI   4      // i-positions per store group
#define NGRP (IT / GI)  // 16 groups
#define TPB  256
#define FPB  (TPB * 5)  // 1280 contiguous features per block
#define WLEN 324        // LDS window length (need 321, pad to 324)

#define TOTAL4 (((size_t)NB * LSEQ * NF) / 4)   // 20,915,200 float4 in d_out

// ---------- diagnostic: fill-clone pure-store sweep (output overwritten later) ----------
__global__ __launch_bounds__(TPB) void store_bench(float4* __restrict__ o) {
    const float4 v = make_float4(1.f, 2.f, 3.f, 4.f);
    size_t idx = (size_t)blockIdx.x * TPB + threadIdx.x;
    const size_t stride = (size_t)gridDim.x * TPB;
    for (; idx < TOTAL4; idx += stride) o[idx] = v;
}

// base pairing score: 2*y0*z3 + 3*y1*z2 + 3*y2*z1 + 2*y3*z0
__device__ __forceinline__ float basescore(const float4 y, const float4 z) {
    return 2.f * y.x * z.w + 3.f * y.y * z.z + 3.f * y.z * z.y + 2.f * y.w * z.x;
}

__global__ __launch_bounds__(TPB) void fdcnn_kernel(const float4* __restrict__ x,
                                                    float* __restrict__ out) {
    // ys[j] = x[i0 + sx + 1 + j]       (y_d for (ii,t,d) at j = ii + t + d-1)
    // zs[j] = x[i0 - sx - 258 + j]     (z_d for (ii,t,d) at j = ii - t - d + 258)
    __shared__ float4 ys[WLEN];
    __shared__ float4 zs[WLEN];
    __shared__ float st[2][GI][FPB];   // 40 KB double-buffered output stage

    const int t = threadIdx.x;
    const int n = blockIdx.z;
    const int bx = blockIdx.x;
    const int i0 = blockIdx.y * IT;
    const int sx = bx * TPB + 2;                    // s of lane 0
    const float4* xg = x + (size_t)n * LSEQ;
    const int fbase = bx * FPB;

    // ---- one-time window fill (the ONLY global loads; drained once below) ----
    for (int j = t; j < WLEN; j += TPB) {
        int py = i0 + sx + 1 + j;                   // >= 3 always
        float4 vy = xg[py > LSEQ - 1 ? LSEQ - 1 : py];
        if (py >= LSEQ) vy = make_float4(0.f, 0.f, 0.f, 0.f);
        ys[j] = vy;
        int pz = i0 - sx - 258 + j;                 // <= 2047 always
        float4 vz = xg[pz < 0 ? 0 : pz];
        if (pz < 0) vz = make_float4(0.f, 0.f, 0.f, 0.f);
        zs[j] = vz;
    }
    __syncthreads();   // full drain OK here: before any output stores exist

    // rolling registers: y1=ys[ii+t], y2=ys[ii+t+1], y3=ys[ii+t+2]
    //                    z1=zs[ii+257-t], z2=zs[ii+256-t], z3=zs[ii+255-t]
    float4 yA = ys[t];          // y1 @ ii=0
    float4 yB = ys[t + 1];      // y2 @ ii=0
    float4 zA = zs[255 - t];    // z3 @ ii=0
    float4 zB = zs[256 - t];    // z2 @ ii=0

    auto compute_group = [&](int g) {
        float* stg = &st[g & 1][0][0];
        #pragma unroll
        for (int ig = 0; ig < GI; ++ig) {
            const int ii = g * GI + ig;
            float4 yC = ys[ii + t + 2];        // new y3
            float4 zC = zs[ii + 257 - t];      // new z1
            const float4 y1 = yA, y2 = yB, y3 = yC;
            const float4 z3 = zA, z2 = zB, z1 = zC;
            float* sp = stg + ig * FPB + t * 5;   // stride-5 dwords: 2 lanes/bank = free
            sp[0] = basescore(y1, z1) + 2.f * (y1.z * z1.w + y1.w * z1.z);  // main + GU
            sp[1] = basescore(y1, z2);   // left bulge d=1
            sp[2] = basescore(y1, z3);   // left bulge d=2
            sp[3] = basescore(y2, z1);   // right bulge d=1
            sp[4] = basescore(y3, z1);   // right bulge d=2
            yA = yB; yB = yC;
            zA = zB; zB = zC;
        }
    };

    compute_group(0);

    for (int g = 0; g < NGRP; ++g) {
        // LDS-only barrier: never drains vmcnt -- output stores stay in flight.
        asm volatile("s_waitcnt lgkmcnt(0)\n\ts_barrier" ::: "memory");

        if (g + 1 < NGRP) compute_group(g + 1);   // fills st[(g+1)&1]

        // store group g from st[g&1]: 5 coalesced float4 per thread, fire-and-forget
        const float* stg = &st[g & 1][0][0];
        float* obase = out + ((size_t)n * LSEQ + (i0 + g * GI)) * (size_t)NF + fbase;
        #pragma unroll
        for (int k = 0; k < 5; ++k) {
            const int v  = k * TPB + t;          // 0..1279 flat float4 index
            const int ig = v / 320;              // 320 float4 per i-row
            const int fo = (v - ig * 320) * 4;   // float offset within block's features
            const int rem = NF - (fbase + fo);
            const float4 val = *(const float4*)(stg + ig * FPB + fo);
            float* dst = obase + (size_t)ig * NF + fo;
            if (rem >= 4) {
                *(float4*)dst = val;
            } else if (rem > 0) {                // feature tail (rem==2)
                dst[0] = val.x;
                if (rem > 1) dst[1] = val.y;
            }
        }
    }
}

extern "C" void kernel_launch(void* const* d_in, const int* in_sizes, int n_in,
                              void* d_out, int out_size, void* d_ws, size_t ws_size,
                              hipStream_t stream) {
    const float4* x = (const float4*)d_in[0];
    float* out = (float*)d_out;

    // DIAGNOSTIC (this round only): two pure-store sweeps over d_out to measure
    // the achievable streaming-write rate from a 1024-block kernel. The real
    // kernel below overwrites every element, so the final output is correct.
    store_bench<<<dim3(1024), dim3(TPB), 0, stream>>>((float4*)d_out);
    store_bench<<<dim3(1024), dim3(TPB), 0, stream>>>((float4*)d_out);

    dim3 grid((NS + TPB - 1) / TPB, LSEQ / IT, NB);  // (4, 32, 8) = 1024 blocks
    dim3 block(TPB);
    fdcnn_kernel<<<grid, block, 0, stream>>>(x, out);
}

// Round 9
// 77.733 us; speedup vs baseline: 2.5055x; 2.5055x over previous
//
#include <hip/hip_runtime.h>

// Problem constants (match reference)
#define LSEQ 2048   // sequence length
#define NS   1022   // number of distances s = 2..1023
#define NF   5110   // NS * 5 output features
#define NB   8      // batch
#define IT   64     // i-positions per block
#define GI   4      // i-positions per store group
#define NGRP (IT / GI)  // 16 groups
#define TPB  256
#define NWAVE 4
#define WSTRIP 320      // floats per wave per i-row (64 lanes * 5)
#define WLEN 132        // per-wave window length (need 129, pad to 132)

// base pairing score: 2*y0*z3 + 3*y1*z2 + 3*y2*z1 + 2*y3*z0
__device__ __forceinline__ float basescore(const float4 y, const float4 z) {
    return 2.f * y.x * z.w + 3.f * y.y * z.z + 3.f * y.z * z.y + 2.f * y.w * z.x;
}

// clamped load: zero outside [0, LSEQ)
__device__ __forceinline__ float4 loadx(const float4* __restrict__ xg, int p) {
    int pc = p < 0 ? 0 : (p > LSEQ - 1 ? LSEQ - 1 : p);
    float4 v = xg[pc];
    if ((unsigned)p >= (unsigned)LSEQ) v = make_float4(0.f, 0.f, 0.f, 0.f);
    return v;
}

// Fully barrier-free: every LDS structure is wave-private. Waves de-phase
// freely so each CU always has stores in flight (continuous write stream).
__global__ __launch_bounds__(TPB, 4) void fdcnn_kernel(const float4* __restrict__ x,
                                                       float* __restrict__ out) {
    __shared__ float4 ysw[NWAVE][WLEN];        // 8.4 KB  y-window per wave
    __shared__ float4 zsw[NWAVE][WLEN];        // 8.4 KB  z-window per wave
    __shared__ float  stg[NWAVE][GI * WSTRIP]; // 20 KB   single-buffered stage

    const int t = threadIdx.x;
    const int w = t >> 6;          // wave id 0..3
    const int l = t & 63;          // lane id
    const int bx = blockIdx.x;
    const int by = blockIdx.y;
    const int n = blockIdx.z;
    const int i0 = by * IT;
    const float4* xg = x + (size_t)n * LSEQ;

    const int s0 = bx * TPB + w * 64 + 2;      // s of this wave's lane 0
    const int fwave = (bx * NWAVE + w) * WSTRIP; // first feature of wave's strip

    // ---- per-wave window fill (only global loads; in-order DS per wave -> no barrier) ----
    const int base_y = i0 + s0 + 1;    // ysw[j] = x[base_y + j]; y_d(ii,l) at j=ii+l+d-1
    const int base_z = i0 - s0 - 66;   // zsw[j] = x[base_z + j]; z_d(ii,l) at j=ii-l+66-d
    #pragma unroll
    for (int j = l; j < 129; j += 64) {
        ysw[w][j] = loadx(xg, base_y + j);
        zsw[w][j] = loadx(xg, base_z + j);
    }

    // rolling registers: y1=ysw[ii+l], y2=ysw[ii+l+1], y3=ysw[ii+l+2]
    //                    z1=zsw[ii+65-l], z2=zsw[ii+64-l], z3=zsw[ii+63-l]
    float4 yA = ysw[w][l];            // y1 @ ii=0
    float4 yB = ysw[w][l + 1];        // y2 @ ii=0
    float4 zA = zsw[w][63 - l];       // z3 @ ii=0
    float4 zB = zsw[w][64 - l];       // z2 @ ii=0

    for (int g = 0; g < NGRP; ++g) {
        // ---- compute phase: GI rows into wave-private stage ----
        #pragma unroll
        for (int ig = 0; ig < GI; ++ig) {
            const int ii = g * GI + ig;
            float4 yC = ysw[w][ii + l + 2];    // new y3
            float4 zC = zsw[w][ii + 65 - l];   // new z1
            const float4 y1 = yA, y2 = yB, y3 = yC;
            const float4 z3 = zA, z2 = zB, z1 = zC;
            float* sp = &stg[w][ig * WSTRIP + l * 5];  // stride-5: 2 lanes/bank = free
            sp[0] = basescore(y1, z1) + 2.f * (y1.z * z1.w + y1.w * z1.z);  // main + GU
            sp[1] = basescore(y1, z2);   // left bulge d=1
            sp[2] = basescore(y1, z3);   // left bulge d=2
            sp[3] = basescore(y2, z1);   // right bulge d=1
            sp[4] = basescore(y3, z1);   // right bulge d=2
            yA = yB; yB = yC;
            zA = zB; zB = zC;
        }

        // ---- store phase: wave reads back its own stage, coalesced dwordx4 ----
        const int ibase = i0 + g * GI;
        float* obase = out + ((size_t)n * LSEQ + ibase) * (size_t)NF + fwave;
        #pragma unroll
        for (int k = 0; k < 5; ++k) {
            const int v  = k * 64 + l;           // 0..319 flat float4 index in wave stage
            const int ig = v / 80;               // 80 float4 per i-row per wave
            const int fo = (v - ig * 80) * 4;    // float offset within wave's strip
            const int rem = NF - (fwave + fo);
            const float4 val = *(const float4*)&stg[w][ig * WSTRIP + fo];
            float* dst = obase + (size_t)ig * NF + fo;
            if (rem >= 4) {
                *(float4*)dst = val;
            } else if (rem > 0) {                // feature tail (rem==2)
                dst[0] = val.x;
                if (rem > 1) dst[1] = val.y;
            }
        }
        // next group's stage writes: same-wave in-order DS + compiler lgkm waits
    }
}

extern "C" void kernel_launch(void* const* d_in, const int* in_sizes, int n_in,
                              void* d_out, int out_size, void* d_ws, size_t ws_size,
                              hipStream_t stream) {
    const float4* x = (const float4*)d_in[0];
    float* out = (float*)d_out;
    dim3 grid(4, LSEQ / IT, NB);   // (4, 32, 8) = 1024 blocks, 37.4 KB LDS -> 4/CU
    dim3 block(TPB);
    fdcnn_kernel<<<grid, block, 0, stream>>>(x, out);
}